// Round 5
// baseline (639.808 us; speedup 1.0000x reference)
//
#include <hip/hip_runtime.h>

#define BB 64
#define NHEADS 4
#define MM 6
#define RR 24        // NHEADS*MM query rows per batch
#define CC 96        // channels
#define NN 12544     // 112*112 spatial
#define DD 192
#define NC 128       // n per chunk
#define TCH 2        // chunks per block
#define NBLK 49      // blocks per batch: 49*2*128 = 12544
#define QSCALE 0.10206207261596577f  // 96^-0.5

typedef __attribute__((ext_vector_type(8))) short short8;
typedef __attribute__((ext_vector_type(4))) float float4v;

__device__ __forceinline__ ushort f2b(float f) {
    union { float f; unsigned int u; } v; v.f = f;
    unsigned int u = v.u;
    unsigned int r = (u + 0x7FFFu + ((u >> 16) & 1u)) >> 16;
    return (ushort)r;
}
__device__ __forceinline__ int swz(int row) { return (row ^ (row >> 3)) & 7; }

// ---- kernel A: Q = (z@Wq + bq)*scale -> bf16 ; zero accumulators ---------
__global__ __launch_bounds__(256) void kA(const float* __restrict__ z,
                                          const float* __restrict__ Wq,
                                          const float* __restrict__ bq,
                                          ushort* __restrict__ Qg,
                                          float* __restrict__ Oacc,
                                          float* __restrict__ sacc) {
    __shared__ float zl[MM * DD];
    int t = threadIdx.x;
    int b = blockIdx.x / 3;
    int rg = blockIdx.x % 3;
    for (int i = t; i < MM * DD; i += 256) zl[i] = z[(size_t)b * MM * DD + i];
    for (int i = t; i < 768; i += 256) Oacc[(size_t)b * RR * CC + rg * 768 + i] = 0.f;
    if (rg == 0 && t < RR) sacc[b * RR + t] = 0.f;
    __syncthreads();
    #pragma unroll
    for (int i = 0; i < 3; ++i) {
        int idx = t + i * 256;            // 0..767 = 8 rows x 96 ch
        int rr = idx / CC;
        int ch = idx - rr * CC;
        int r = rg * 8 + rr;
        int h = r / MM, m = r - h * MM;
        int col = h * CC + ch;
        float acc = bq[col];
        #pragma unroll 4
        for (int k = 0; k < DD; ++k)
            acc += zl[m * DD + k] * Wq[(size_t)k * (NHEADS * CC) + col];
        Qg[((size_t)b * RR + r) * CC + ch] = f2b(acc * QSCALE);
    }
}

// ---- kernel B: full-MFMA fused attention, 2 chunks, reg-prefetch ---------
// xs layout: row ch (stride 128 elems), 8-elem chunk at phys = (n>>3) ^ swz(ch)
// es layout: same with row r (24 rows)
__global__ __launch_bounds__(256, 4) void kB(const float* __restrict__ x,
                                             const ushort* __restrict__ Qg,
                                             float* __restrict__ Oacc,
                                             float* __restrict__ sacc) {
    __shared__ ushort xs[CC * NC];       // 24576 B
    __shared__ ushort es[RR * NC];       // 6144 B
    __shared__ ushort Qs[RR * 104];      // 4992 B (stride 104: bank spread)
    __shared__ float sdenW[4 * RR];      // 384 B

    int t = threadIdx.x;
    int b = blockIdx.x / NBLK;
    int blk = blockIdx.x - b * NBLK;
    int w = t >> 6, lane = t & 63, q = lane >> 4, l15 = lane & 15;

    const float* xgb = x + (size_t)b * CC * NN + (size_t)blk * TCH * NC;

    // decompose staging indices once
    int sch[12], sj4[12];
    #pragma unroll
    for (int i = 0; i < 12; ++i) {
        int cc = t + i * 256;            // 0..3071: 96 rows x 32 float4-groups
        sch[i] = cc >> 5;
        sj4[i] = cc & 31;
    }

    // ---- prefetch chunk 0 ----
    float4 pf[12];
    #pragma unroll
    for (int i = 0; i < 12; ++i)
        pf[i] = *(const float4*)(xgb + (size_t)sch[i] * NN + sj4[i] * 4);

    // ---- stage Q into LDS (global loads issued after pf: only used post-wait)
    for (int i = t; i < RR * CC; i += 256) {
        int r = i / CC, ch = i - r * CC;
        Qs[r * 104 + ch] = Qg[(size_t)b * RR * CC + i];
    }

    int rt2 = w & 1;                     // pass2: r-tile of this wave
    int ct0 = (w >> 1) * 3;              // pass2: first of 3 ch-tiles
    float4v oacc0 = {0.f,0.f,0.f,0.f}, oacc1 = {0.f,0.f,0.f,0.f}, oacc2 = {0.f,0.f,0.f,0.f};
    float pden[8] = {0.f,0.f,0.f,0.f,0.f,0.f,0.f,0.f};

    int qr0 = l15;                                  // pass1 A rows
    int qr1 = (16 + l15 > 23) ? 23 : 16 + l15;      // clamp (dup row 23, discarded)

    for (int c = 0; c < TCH; ++c) {
        // ---- convert prefetched regs, store to xs (8B swizzled) ----
        #pragma unroll
        for (int i = 0; i < 12; ++i) {
            ushort4 wv;
            wv.x = f2b(pf[i].x); wv.y = f2b(pf[i].y);
            wv.z = f2b(pf[i].z); wv.w = f2b(pf[i].w);
            int phys = (sj4[i] >> 1) ^ swz(sch[i]);
            *(ushort4*)(&xs[sch[i] * NC + phys * 8 + (sj4[i] & 1) * 4]) = wv;
        }
        __syncthreads();                             // B1

        // ---- issue prefetch for next chunk (has pass1+pass2 to land) ----
        if (c + 1 < TCH) {
            const float* xg = xgb + (size_t)(c + 1) * NC;
            #pragma unroll
            for (int i = 0; i < 12; ++i)
                pf[i] = *(const float4*)(xg + (size_t)sch[i] * NN + sj4[i] * 4);
        }

        // ---- pass 1: S(24x128) = Q @ X via MFMA; wave w owns n-tiles 2w,2w+1
        float4v s00 = {0.f,0.f,0.f,0.f}, s01 = {0.f,0.f,0.f,0.f};
        float4v s10 = {0.f,0.f,0.f,0.f}, s11 = {0.f,0.f,0.f,0.f};
        #pragma unroll
        for (int kt = 0; kt < 3; ++kt) {
            short8 bf0, bf1;
            #pragma unroll
            for (int ntj = 0; ntj < 2; ++ntj) {
                int n = (2 * w + ntj) * 16 + l15;
                int chL = n >> 3, nin = n & 7;
                short8 bf;
                #pragma unroll
                for (int j = 0; j < 8; ++j) {
                    int R = kt * 32 + q * 8 + j;
                    bf[j] = (short)xs[R * NC + ((chL ^ swz(R)) << 3) + nin];
                }
                if (ntj == 0) bf0 = bf; else bf1 = bf;
            }
            short8 af0 = *(const short8*)(&Qs[qr0 * 104 + kt * 32 + q * 8]);
            short8 af1 = *(const short8*)(&Qs[qr1 * 104 + kt * 32 + q * 8]);
            s00 = __builtin_amdgcn_mfma_f32_16x16x32_bf16(af0, bf0, s00, 0, 0, 0);
            s01 = __builtin_amdgcn_mfma_f32_16x16x32_bf16(af0, bf1, s01, 0, 0, 0);
            s10 = __builtin_amdgcn_mfma_f32_16x16x32_bf16(af1, bf0, s10, 0, 0, 0);
            s11 = __builtin_amdgcn_mfma_f32_16x16x32_bf16(af1, bf1, s11, 0, 0, 0);
        }

        // ---- exp -> es (swizzled, masked r<24), register denominators ----
        #pragma unroll
        for (int rt = 0; rt < 2; ++rt) {
            #pragma unroll
            for (int ntj = 0; ntj < 2; ++ntj) {
                float4v sv = rt == 0 ? (ntj == 0 ? s00 : s01) : (ntj == 0 ? s10 : s11);
                int n = (2 * w + ntj) * 16 + l15;
                int chLn = n >> 3, nin = n & 7;
                #pragma unroll
                for (int reg = 0; reg < 4; ++reg) {
                    int r = rt * 16 + q * 4 + reg;
                    if (r < RR) {
                        float e = __expf(fminf(fmaxf(sv[reg], -30.f), 30.f));
                        es[r * NC + ((chLn ^ swz(r)) << 3) + nin] = f2b(e);
                        pden[rt * 4 + reg] += e;
                    }
                }
            }
        }
        __syncthreads();                             // B2

        // ---- pass 2: O(24x96) += E(24x128) @ X^T, reg-accumulated ----
        int ar = rt2 * 16 + l15; if (ar > 23) ar = 23;
        int cr0 = (ct0 + 0) * 16 + l15;
        int cr1 = (ct0 + 1) * 16 + l15;
        int cr2 = (ct0 + 2) * 16 + l15;
        #pragma unroll
        for (int kt = 0; kt < 4; ++kt) {
            int chL = kt * 4 + q;                    // (kt*32+q*8)>>3
            short8 af = *(const short8*)(&es[ar * NC + ((chL ^ swz(ar)) << 3)]);
            short8 b0 = *(const short8*)(&xs[cr0 * NC + ((chL ^ swz(cr0)) << 3)]);
            short8 b1 = *(const short8*)(&xs[cr1 * NC + ((chL ^ swz(cr1)) << 3)]);
            short8 b2 = *(const short8*)(&xs[cr2 * NC + ((chL ^ swz(cr2)) << 3)]);
            oacc0 = __builtin_amdgcn_mfma_f32_16x16x32_bf16(af, b0, oacc0, 0, 0, 0);
            oacc1 = __builtin_amdgcn_mfma_f32_16x16x32_bf16(af, b1, oacc1, 0, 0, 0);
            oacc2 = __builtin_amdgcn_mfma_f32_16x16x32_bf16(af, b2, oacc2, 0, 0, 0);
        }
        __syncthreads();                             // B3
    }

    // ---- epilogue: denominator reduce (shuffle -> LDS -> 24 atomics) ----
    #pragma unroll
    for (int rt = 0; rt < 2; ++rt) {
        #pragma unroll
        for (int reg = 0; reg < 4; ++reg) {
            float v = pden[rt * 4 + reg];
            v += __shfl_xor(v, 1, 64); v += __shfl_xor(v, 2, 64);
            v += __shfl_xor(v, 4, 64); v += __shfl_xor(v, 8, 64);
            int row = rt * 16 + q * 4 + reg;
            if (l15 == 0 && row < RR) sdenW[w * RR + row] = v;
        }
    }
    __syncthreads();
    if (t < RR)
        atomicAdd(&sacc[b * RR + t],
                  sdenW[t] + sdenW[RR + t] + sdenW[2 * RR + t] + sdenW[3 * RR + t]);

    // ---- O partial atomics ----
    #pragma unroll
    for (int reg = 0; reg < 4; ++reg) {
        int r = rt2 * 16 + q * 4 + reg;              // C/D: row=quad*4+reg, col=l15
        if (r < RR) {
            size_t base = ((size_t)b * RR + r) * CC + l15;
            atomicAdd(&Oacc[base + (ct0 + 0) * 16], oacc0[reg]);
            atomicAdd(&Oacc[base + (ct0 + 1) * 16], oacc1[reg]);
            atomicAdd(&Oacc[base + (ct0 + 2) * 16], oacc2[reg]);
        }
    }
}

// ---- kernel C: out = z + (O/sden)@Wo + bo --------------------------------
__global__ __launch_bounds__(192) void kC(const float* __restrict__ z,
                                          const float* __restrict__ Wo,
                                          const float* __restrict__ bo,
                                          const float* __restrict__ Oacc,
                                          const float* __restrict__ sacc,
                                          float* __restrict__ out) {
    __shared__ float oh[NHEADS * CC];   // 384
    int t = threadIdx.x;
    int b = blockIdx.x / MM;
    int m = blockIdx.x - b * MM;
    for (int i = t; i < NHEADS * CC; i += 192) {
        int h = i / CC, ch = i - h * CC;
        int r = h * MM + m;
        oh[i] = Oacc[((size_t)b * RR + r) * CC + ch] / sacc[b * RR + r];
    }
    __syncthreads();
    int d = t;
    float acc = bo[d] + z[((size_t)b * MM + m) * DD + d];
    #pragma unroll 8
    for (int k = 0; k < NHEADS * CC; ++k)
        acc += oh[k] * Wo[(size_t)k * DD + d];
    out[((size_t)b * MM + m) * DD + d] = acc;
}

extern "C" void kernel_launch(void* const* d_in, const int* in_sizes, int n_in,
                              void* d_out, int out_size, void* d_ws, size_t ws_size,
                              hipStream_t stream) {
    const float* x  = (const float*)d_in[0];
    const float* z  = (const float*)d_in[1];
    const float* Wq = (const float*)d_in[2];
    const float* bq = (const float*)d_in[3];
    const float* Wo = (const float*)d_in[4];
    const float* bo = (const float*)d_in[5];

    ushort* Qg  = (ushort*)d_ws;                          // 64*24*96 bf16
    float* Oacc = (float*)((char*)d_ws + 294912);         // 64*24*96 f32
    float* sacc = (float*)((char*)d_ws + 294912 + 589824);// 64*24    f32

    kA<<<BB * 3, 256, 0, stream>>>(z, Wq, bq, Qg, Oacc, sacc);
    kB<<<BB * NBLK, 256, 0, stream>>>(x, Qg, Oacc, sacc);
    kC<<<BB * MM, 192, 0, stream>>>(z, Wo, bo, Oacc, sacc, (float*)d_out);
}

// Round 6
// 494.010 us; speedup vs baseline: 1.2951x; 1.2951x over previous
//
#include <hip/hip_runtime.h>

#define BB 64
#define NHEADS 4
#define MM 6
#define RR 24        // NHEADS*MM query rows per batch
#define CC 96        // channels
#define NN 12544     // 112*112 spatial
#define DD 192
#define NC 128       // n per block
#define NBLK 98      // blocks per batch: 98*128 = 12544
#define QSCALE 0.10206207261596577f  // 96^-0.5

typedef __attribute__((ext_vector_type(8))) short short8;
typedef __attribute__((ext_vector_type(4))) float float4v;

__device__ __forceinline__ ushort f2b(float f) {
    union { float f; unsigned int u; } v; v.f = f;
    unsigned int u = v.u;
    unsigned int r = (u + 0x7FFFu + ((u >> 16) & 1u)) >> 16;
    return (ushort)r;
}
__device__ __forceinline__ int swz(int row) { return (row ^ (row >> 3)) & 7; }

// ---- kernel A: Q = (z@Wq + bq)*scale -> bf16 ; zero accumulators ---------
__global__ __launch_bounds__(256) void kA(const float* __restrict__ z,
                                          const float* __restrict__ Wq,
                                          const float* __restrict__ bq,
                                          ushort* __restrict__ Qg,
                                          float* __restrict__ Oacc,
                                          float* __restrict__ sacc) {
    __shared__ float zl[MM * DD];
    int t = threadIdx.x;
    int b = blockIdx.x / 3;
    int rg = blockIdx.x % 3;
    for (int i = t; i < MM * DD; i += 256) zl[i] = z[(size_t)b * MM * DD + i];
    for (int i = t; i < 768; i += 256) Oacc[(size_t)b * RR * CC + rg * 768 + i] = 0.f;
    if (rg == 0 && t < RR) sacc[b * RR + t] = 0.f;
    __syncthreads();
    #pragma unroll
    for (int i = 0; i < 3; ++i) {
        int idx = t + i * 256;            // 0..767 = 8 rows x 96 ch
        int rr = idx / CC;
        int ch = idx - rr * CC;
        int r = rg * 8 + rr;
        int h = r / MM, m = r - h * MM;
        int col = h * CC + ch;
        float acc = bq[col];
        #pragma unroll 4
        for (int k = 0; k < DD; ++k)
            acc += zl[m * DD + k] * Wq[(size_t)k * (NHEADS * CC) + col];
        Qg[((size_t)b * RR + r) * CC + ch] = f2b(acc * QSCALE);
    }
}

// ---- kernel B: full-MFMA fused attention, one 128-column chunk per block -
// xs layout: row ch (stride 128 elems), 8-elem group at phys = (n>>3) ^ swz(ch)
// es layout: same with row r (24 rows)
__global__ __launch_bounds__(256, 4) void kB(const float* __restrict__ x,
                                             const ushort* __restrict__ Qg,
                                             float* __restrict__ Oacc,
                                             float* __restrict__ sacc) {
    __shared__ ushort xs[CC * NC];       // 24576 B
    __shared__ ushort es[RR * NC];       // 6144 B
    __shared__ ushort Qs[RR * 104];      // 4992 B (stride 104: bank spread)
    __shared__ float sdenW[4 * RR];      // 384 B

    int t = threadIdx.x;
    int b = blockIdx.x / NBLK;
    int blk = blockIdx.x - b * NBLK;
    int w = t >> 6, lane = t & 63, q = lane >> 4, l15 = lane & 15;

    const float* xg = x + (size_t)b * CC * NN + (size_t)blk * NC;

    // ---- issue x chunk loads (12 float4/thread), then Q stage ----
    float4 pf[12];
    int sch[12], sj4[12];
    #pragma unroll
    for (int i = 0; i < 12; ++i) {
        int cc = t + i * 256;            // 0..3071: 96 rows x 32 float4-groups
        sch[i] = cc >> 5;
        sj4[i] = cc & 31;
        pf[i] = *(const float4*)(xg + (size_t)sch[i] * NN + sj4[i] * 4);
    }
    // Q stage: 576 ushort4 (8B) transfers
    #pragma unroll
    for (int i = t; i < 576; i += 256) {
        int i4 = i * 4;
        int r = i4 / CC, ch = i4 - r * CC;
        *(ushort4*)(&Qs[r * 104 + ch]) = *(const ushort4*)(Qg + (size_t)b * RR * CC + i4);
    }
    // convert + swizzled store to xs (pressure peak is here only)
    #pragma unroll
    for (int i = 0; i < 12; ++i) {
        ushort4 wv;
        wv.x = f2b(pf[i].x); wv.y = f2b(pf[i].y);
        wv.z = f2b(pf[i].z); wv.w = f2b(pf[i].w);
        int phys = (sj4[i] >> 1) ^ swz(sch[i]);
        *(ushort4*)(&xs[sch[i] * NC + phys * 8 + (sj4[i] & 1) * 4]) = wv;
    }
    __syncthreads();                                  // B1

    // ---- pass 1: S(24x128) = Q @ X via MFMA; wave w owns n-tiles 2w,2w+1 --
    int qr0 = l15;
    int qr1 = (16 + l15 > 23) ? 23 : 16 + l15;        // clamp (dup row, discarded)
    float4v s00 = {0.f,0.f,0.f,0.f}, s01 = {0.f,0.f,0.f,0.f};
    float4v s10 = {0.f,0.f,0.f,0.f}, s11 = {0.f,0.f,0.f,0.f};
    #pragma unroll
    for (int kt = 0; kt < 3; ++kt) {
        short8 bf0, bf1;
        #pragma unroll
        for (int ntj = 0; ntj < 2; ++ntj) {
            int n = (2 * w + ntj) * 16 + l15;
            int chL = n >> 3, nin = n & 7;
            short8 bf;
            #pragma unroll
            for (int j = 0; j < 8; ++j) {
                int R = kt * 32 + q * 8 + j;
                bf[j] = (short)xs[R * NC + ((chL ^ swz(R)) << 3) + nin];
            }
            if (ntj == 0) bf0 = bf; else bf1 = bf;
        }
        short8 af0 = *(const short8*)(&Qs[qr0 * 104 + kt * 32 + q * 8]);
        short8 af1 = *(const short8*)(&Qs[qr1 * 104 + kt * 32 + q * 8]);
        s00 = __builtin_amdgcn_mfma_f32_16x16x32_bf16(af0, bf0, s00, 0, 0, 0);
        s01 = __builtin_amdgcn_mfma_f32_16x16x32_bf16(af0, bf1, s01, 0, 0, 0);
        s10 = __builtin_amdgcn_mfma_f32_16x16x32_bf16(af1, bf0, s10, 0, 0, 0);
        s11 = __builtin_amdgcn_mfma_f32_16x16x32_bf16(af1, bf1, s11, 0, 0, 0);
    }

    // ---- exp -> es (swizzled, r<24), register denominators ----
    float pden[8] = {0.f,0.f,0.f,0.f,0.f,0.f,0.f,0.f};
    #pragma unroll
    for (int rt = 0; rt < 2; ++rt) {
        #pragma unroll
        for (int ntj = 0; ntj < 2; ++ntj) {
            float4v sv = rt == 0 ? (ntj == 0 ? s00 : s01) : (ntj == 0 ? s10 : s11);
            int n = (2 * w + ntj) * 16 + l15;
            int chLn = n >> 3, nin = n & 7;
            #pragma unroll
            for (int reg = 0; reg < 4; ++reg) {
                int r = rt * 16 + q * 4 + reg;
                if (r < RR) {
                    float e = __expf(fminf(fmaxf(sv[reg], -30.f), 30.f));
                    es[r * NC + ((chLn ^ swz(r)) << 3) + nin] = f2b(e);
                    pden[rt * 4 + reg] += e;
                }
            }
        }
    }
    __syncthreads();                                  // B2

    // ---- pass 2: O(24x96) = E(24x128) @ X^T via MFMA ----
    int rt2 = w & 1;
    int ct0 = (w >> 1) * 3;
    float4v oacc0 = {0.f,0.f,0.f,0.f}, oacc1 = {0.f,0.f,0.f,0.f}, oacc2 = {0.f,0.f,0.f,0.f};
    int ar = rt2 * 16 + l15; if (ar > 23) ar = 23;
    int cr0 = (ct0 + 0) * 16 + l15;
    int cr1 = (ct0 + 1) * 16 + l15;
    int cr2 = (ct0 + 2) * 16 + l15;
    #pragma unroll
    for (int kt = 0; kt < 4; ++kt) {
        int chL = kt * 4 + q;                         // (kt*32+q*8)>>3
        short8 af = *(const short8*)(&es[ar * NC + ((chL ^ swz(ar)) << 3)]);
        short8 b0 = *(const short8*)(&xs[cr0 * NC + ((chL ^ swz(cr0)) << 3)]);
        short8 b1 = *(const short8*)(&xs[cr1 * NC + ((chL ^ swz(cr1)) << 3)]);
        short8 b2 = *(const short8*)(&xs[cr2 * NC + ((chL ^ swz(cr2)) << 3)]);
        oacc0 = __builtin_amdgcn_mfma_f32_16x16x32_bf16(af, b0, oacc0, 0, 0, 0);
        oacc1 = __builtin_amdgcn_mfma_f32_16x16x32_bf16(af, b1, oacc1, 0, 0, 0);
        oacc2 = __builtin_amdgcn_mfma_f32_16x16x32_bf16(af, b2, oacc2, 0, 0, 0);
    }

    // ---- epilogue: denominator reduce (shuffle -> LDS -> 24 atomics) ----
    #pragma unroll
    for (int rt = 0; rt < 2; ++rt) {
        #pragma unroll
        for (int reg = 0; reg < 4; ++reg) {
            float v = pden[rt * 4 + reg];
            v += __shfl_xor(v, 1, 64); v += __shfl_xor(v, 2, 64);
            v += __shfl_xor(v, 4, 64); v += __shfl_xor(v, 8, 64);
            int row = rt * 16 + q * 4 + reg;
            if (l15 == 0 && row < RR) sdenW[w * RR + row] = v;
        }
    }
    __syncthreads();
    if (t < RR)
        atomicAdd(&sacc[b * RR + t],
                  sdenW[t] + sdenW[RR + t] + sdenW[2 * RR + t] + sdenW[3 * RR + t]);

    // ---- O partial atomics ----
    #pragma unroll
    for (int reg = 0; reg < 4; ++reg) {
        int r = rt2 * 16 + q * 4 + reg;               // C/D: row=quad*4+reg, col=l15
        if (r < RR) {
            size_t base = ((size_t)b * RR + r) * CC + l15;
            atomicAdd(&Oacc[base + (ct0 + 0) * 16], oacc0[reg]);
            atomicAdd(&Oacc[base + (ct0 + 1) * 16], oacc1[reg]);
            atomicAdd(&Oacc[base + (ct0 + 2) * 16], oacc2[reg]);
        }
    }
}

// ---- kernel C: out = z + (O/sden)@Wo + bo --------------------------------
__global__ __launch_bounds__(192) void kC(const float* __restrict__ z,
                                          const float* __restrict__ Wo,
                                          const float* __restrict__ bo,
                                          const float* __restrict__ Oacc,
                                          const float* __restrict__ sacc,
                                          float* __restrict__ out) {
    __shared__ float oh[NHEADS * CC];   // 384
    int t = threadIdx.x;
    int b = blockIdx.x / MM;
    int m = blockIdx.x - b * MM;
    for (int i = t; i < NHEADS * CC; i += 192) {
        int h = i / CC, ch = i - h * CC;
        int r = h * MM + m;
        oh[i] = Oacc[((size_t)b * RR + r) * CC + ch] / sacc[b * RR + r];
    }
    __syncthreads();
    int d = t;
    float acc = bo[d] + z[((size_t)b * MM + m) * DD + d];
    #pragma unroll 8
    for (int k = 0; k < NHEADS * CC; ++k)
        acc += oh[k] * Wo[(size_t)k * DD + d];
    out[((size_t)b * MM + m) * DD + d] = acc;
}

extern "C" void kernel_launch(void* const* d_in, const int* in_sizes, int n_in,
                              void* d_out, int out_size, void* d_ws, size_t ws_size,
                              hipStream_t stream) {
    const float* x  = (const float*)d_in[0];
    const float* z  = (const float*)d_in[1];
    const float* Wq = (const float*)d_in[2];
    const float* bq = (const float*)d_in[3];
    const float* Wo = (const float*)d_in[4];
    const float* bo = (const float*)d_in[5];

    ushort* Qg  = (ushort*)d_ws;                          // 64*24*96 bf16
    float* Oacc = (float*)((char*)d_ws + 294912);         // 64*24*96 f32
    float* sacc = (float*)((char*)d_ws + 294912 + 589824);// 64*24    f32

    kA<<<BB * 3, 256, 0, stream>>>(z, Wq, bq, Qg, Oacc, sacc);
    kB<<<BB * NBLK, 256, 0, stream>>>(x, Qg, Oacc, sacc);
    kC<<<BB * MM, 192, 0, stream>>>(z, Wo, bo, Oacc, sacc, (float*)d_out);
}